// Round 12
// baseline (624.631 us; speedup 1.0000x reference)
//
#include <hip/hip_runtime.h>

#define DD 256
#define KK 8192
#define HW 1024
#define NROWS 16384
#define NELEM 4194304
#define MT 32
#define MARGIN 6e-4f
#define WCAP 512

typedef __attribute__((ext_vector_type(8))) short short8;
typedef __attribute__((ext_vector_type(4))) float f32x4;
typedef unsigned short ushort;
typedef unsigned int uint;
typedef unsigned long long u64;

// ---- exact replication of numpy pairwise_sum (n=256) over squares ----
__device__ __forceinline__ float np_pw128_sq(const float* p) {
  float r[8];
#pragma unroll
  for (int j = 0; j < 8; ++j) r[j] = __fmul_rn(p[j], p[j]);
  for (int i = 8; i < 128; i += 8) {
#pragma unroll
    for (int j = 0; j < 8; ++j)
      r[j] = __fadd_rn(r[j], __fmul_rn(p[i + j], p[i + j]));
  }
  return __fadd_rn(__fadd_rn(__fadd_rn(r[0], r[1]), __fadd_rn(r[2], r[3])),
                   __fadd_rn(__fadd_rn(r[4], r[5]), __fadd_rn(r[6], r[7])));
}

__device__ __forceinline__ ushort f2bf(float x) {   // RNE float->bf16 bits
  uint u = __float_as_uint(x);
  u += 0x7FFF + ((u >> 16) & 1);
  return (ushort)(u >> 16);
}

// ======== merged prep: transpose | norms | arow | cbB fragments ========
__global__ __launch_bounds__(256) void vq_prep(const float* __restrict__ z,
                                               const float* __restrict__ cb,
                                               float* __restrict__ cbT,
                                               float* __restrict__ Bk,
                                               float* __restrict__ Arow,
                                               ushort* __restrict__ cbB) {
  __shared__ float tile[64][65];
  const int b = blockIdx.x, t = threadIdx.x;
  if (b < 512) {               // cbT[d][k] = cb[k][d]
    int k0 = (b & 127) * 64, d0 = (b >> 7) * 64;
    for (int li = t; li < 64 * 64; li += 256) {
      int kk = li >> 6, dd = li & 63;
      tile[kk][dd] = cb[(size_t)(k0 + kk) * DD + d0 + dd];
    }
    __syncthreads();
    for (int li = t; li < 64 * 64; li += 256) {
      int dd = li >> 6, kk = li & 63;
      cbT[(size_t)(d0 + dd) * KK + k0 + kk] = tile[kk][dd];
    }
  } else if (b < 544) {        // ||e_k||^2, numpy-exact
    int k = (b - 512) * 256 + t;
    const float* p = cb + (size_t)k * DD;
    Bk[k] = __fadd_rn(np_pw128_sq(p), np_pw128_sq(p + 128));
  } else if (b < 608) {        // ||z_n||^2, numpy-exact (strided)
    int n = (b - 544) * 256 + t;
    int bimg = n >> 10, hw = n & 1023;
    const float* zp = z + (size_t)bimg * DD * HW + hw;
    float h[2];
#pragma unroll
    for (int half = 0; half < 2; ++half) {
      float r[8];
#pragma unroll
      for (int j = 0; j < 8; ++j) {
        float v = zp[(size_t)(half * 128 + j) * HW];
        r[j] = __fmul_rn(v, v);
      }
      for (int i = 8; i < 128; i += 8) {
#pragma unroll
        for (int j = 0; j < 8; ++j) {
          float v = zp[(size_t)(half * 128 + i + j) * HW];
          r[j] = __fadd_rn(r[j], __fmul_rn(v, v));
        }
      }
      h[half] = __fadd_rn(__fadd_rn(__fadd_rn(r[0], r[1]), __fadd_rn(r[2], r[3])),
                          __fadd_rn(__fadd_rn(r[4], r[5]), __fadd_rn(r[6], r[7])));
    }
    Arow[n] = __fadd_rn(h[0], h[1]);
  } else {                     // cbB fragments (layout verified r7-r11)
    int tid = (b - 608) * 256 + t;
    int g = tid >> 9, s = (tid >> 6) & 7, lane = tid & 63;
    int code = g * 16 + (lane & 15);
    int dbase = s * 32 + (lane >> 4) * 8;
    const float* p = cb + (size_t)code * DD + dbase;
    ushort bb[8];
#pragma unroll
    for (int j = 0; j < 8; ++j) bb[j] = f2bf(p[j]);
    uint4 pk;
    pk.x = bb[0] | ((uint)bb[1] << 16);
    pk.y = bb[2] | ((uint)bb[3] << 16);
    pk.z = bb[4] | ((uint)bb[5] << 16);
    pk.w = bb[6] | ((uint)bb[7] << 16);
    *(uint4*)(cbB + (size_t)tid * 8) = pk;
  }
}

// ======== fused: XCD-parity-split MFMA screen + exact + late epilogue ======
// grid 1024: block b -> rows (b>>1)*32..+32, k-half (b&1)*4096..+4096.
// With round-robin XCD assignment (XCD ~ b%8), b&1 is constant per XCD ->
// each XCD streams the SAME 2.1 MB cbB half -> L2-resident (r11: 4.2 MB/block
// thrashed the 4 MiB per-XCD L2 -> 716 MB L3 traffic = the whole runtime).
// Plain launch_bounds (r4/r5 lesson: min-waves arg caps VGPRs -> spill).
__global__ __launch_bounds__(256) void vq_fused(
    const float* __restrict__ z, const float* __restrict__ cbT,
    const float* __restrict__ cb, const ushort* __restrict__ cbB,
    const float* __restrict__ Bk, const float* __restrict__ Arow,
    float* __restrict__ out, int* __restrict__ hist,
    float* __restrict__ loss_acc, u64* __restrict__ rowBest,
    int* __restrict__ flags) {
  __shared__ float zt[MT][DD + 1];    // 32.9 KB, staged once, lives to the end
  __shared__ float gmin[MT][65];      // 8.3 KB: my half's 64 64-code tiles
  __shared__ float thr[MT];
  __shared__ float ArS[MT];
  __shared__ int wl[WCAP];
  __shared__ int wcnt;
  __shared__ int kwin[MT];
  __shared__ float lred[4];
  __shared__ int amLast;

  const int t = threadIdx.x;
  const int rowTile = blockIdx.x >> 1;
  const int khalf = blockIdx.x & 1;
  const int n0 = rowTile * MT;
  const int bimg = n0 >> 10, hw0 = n0 & 1023;
  const float* zb = z + (size_t)bimg * DD * HW + hw0;

  if (t == 0) wcnt = 0;
  if (t < MT) ArS[t] = Arow[n0 + t];
  for (int li = t; li < MT * DD; li += 256) {
    int d = li >> 5, r = li & 31;
    zt[r][d] = zb[d * HW + r];
  }
  __syncthreads();

  const int w = t >> 6, lane = t & 63;
  const int quad = lane >> 4, n16 = lane & 15;

  // A-fragments for BOTH 16-row groups (m89-verified layout), in registers
  short8 aF[2][8];
#pragma unroll
  for (int rg = 0; rg < 2; ++rg)
#pragma unroll
    for (int s = 0; s < 8; ++s) {
      const float* zp = &zt[rg * 16 + n16][s * 32 + quad * 8];
      short8 v;
#pragma unroll
      for (int j = 0; j < 8; ++j) v[j] = (short)f2bf(zp[j]);
      aF[rg][s] = v;
    }

  // ---- screen: wave owns 1024 codes = 64 groups of 16; no barriers ----
  const int g0 = khalf * 256 + w * 64;   // global 16-code group
  float m40[4] = {3.4e38f, 3.4e38f, 3.4e38f, 3.4e38f};
  float m41[4] = {3.4e38f, 3.4e38f, 3.4e38f, 3.4e38f};

  short8 b0[8], b1[8];
  {
    const ushort* bp = cbB + (size_t)g0 * 4096 + lane * 8;
#pragma unroll
    for (int s = 0; s < 8; ++s) b0[s] = *(const short8*)(bp + s * 512);
  }

  for (int gp = 0; gp < 32; ++gp) {     // hand-pipelined pairs: b0/b1 ping-pong
    const int gg = g0 + gp * 2;
    {   // prefetch odd group while even computes
      const ushort* bp = cbB + (size_t)(gg + 1) * 4096 + lane * 8;
#pragma unroll
      for (int s = 0; s < 8; ++s) b1[s] = *(const short8*)(bp + s * 512);
    }
    {   // even group
      f32x4 a0 = {0.f, 0.f, 0.f, 0.f}, a1 = {0.f, 0.f, 0.f, 0.f};
#pragma unroll
      for (int s = 0; s < 8; ++s) {
        a0 = __builtin_amdgcn_mfma_f32_16x16x32_bf16(aF[0][s], b0[s], a0, 0, 0, 0);
        a1 = __builtin_amdgcn_mfma_f32_16x16x32_bf16(aF[1][s], b0[s], a1, 0, 0, 0);
      }
      const float Bs = Bk[gg * 16 + n16];
#pragma unroll
      for (int reg = 0; reg < 4; ++reg) {
        m40[reg] = fminf(m40[reg], fmaf(-2.f, a0[reg], Bs));
        m41[reg] = fminf(m41[reg], fmaf(-2.f, a1[reg], Bs));
      }
    }
    if (gp < 31) {   // prefetch next even group while odd computes
      const ushort* bp = cbB + (size_t)(gg + 2) * 4096 + lane * 8;
#pragma unroll
      for (int s = 0; s < 8; ++s) b0[s] = *(const short8*)(bp + s * 512);
    }
    {   // odd group
      f32x4 a0 = {0.f, 0.f, 0.f, 0.f}, a1 = {0.f, 0.f, 0.f, 0.f};
#pragma unroll
      for (int s = 0; s < 8; ++s) {
        a0 = __builtin_amdgcn_mfma_f32_16x16x32_bf16(aF[0][s], b1[s], a0, 0, 0, 0);
        a1 = __builtin_amdgcn_mfma_f32_16x16x32_bf16(aF[1][s], b1[s], a1, 0, 0, 0);
      }
      const float Bs = Bk[(gg + 1) * 16 + n16];
#pragma unroll
      for (int reg = 0; reg < 4; ++reg) {
        m40[reg] = fminf(m40[reg], fmaf(-2.f, a0[reg], Bs));
        m41[reg] = fminf(m41[reg], fmaf(-2.f, a1[reg], Bs));
      }
    }
    if (gp & 1) {    // 4 groups (64 codes) done: reduce over 16 code-lanes
#pragma unroll
      for (int off = 1; off < 16; off <<= 1)
#pragma unroll
        for (int reg = 0; reg < 4; ++reg) {
          m40[reg] = fminf(m40[reg], __shfl_xor(m40[reg], off));
          m41[reg] = fminf(m41[reg], __shfl_xor(m41[reg], off));
        }
      if (n16 == 0) {
        const int tileL = w * 16 + (gp >> 1);   // local 64-code tile 0..63
#pragma unroll
        for (int reg = 0; reg < 4; ++reg) {
          gmin[quad * 4 + reg][tileL] = m40[reg];
          gmin[16 + quad * 4 + reg][tileL] = m41[reg];
        }
      }
#pragma unroll
      for (int reg = 0; reg < 4; ++reg) { m40[reg] = 3.4e38f; m41[reg] = 3.4e38f; }
    }
  }
  __syncthreads();

  // ---- per-row threshold (local half min: conservative, correct) ----
  if (t < MT) {
    float mn = gmin[t][0];
    for (int c = 1; c < 64; ++c) mn = fminf(mn, gmin[t][c]);
    thr[t] = mn + MARGIN;
  }
  __syncthreads();

  // ---- worklist build (g stored as GLOBAL 64-code tile) ----
  for (int idx = t; idx < MT * 64; idx += 256) {
    int r = idx >> 6, gl = idx & 63;
    if (gmin[r][gl] <= thr[r]) {
      int g = khalf * 64 + gl;
      int pos = atomicAdd(&wcnt, 1);
      if (pos < WCAP) {
        wl[pos] = (r << 16) | g;
      } else {   // overflow fallback (never in practice): scalar exact scan
        float bd = 3.4e38f;
        int bi = 0;
        for (int c = 0; c < 64; ++c) {
          int code = g * 64 + c;
          const float* ep = cb + (size_t)code * DD;
          float dot = 0.f;
          for (int d = 0; d < DD; ++d) dot = fmaf(zt[r][d], ep[d], dot);
          float dist = __fsub_rn(__fadd_rn(ArS[r], Bk[code]),
                                 __fmul_rn(2.f, dot));
          if (dist < bd) { bd = dist; bi = code; }
        }
        atomicMin(&rowBest[n0 + r],
                  ((u64)__float_as_uint(bd) << 32) | (unsigned)bi);
      }
    }
  }
  __syncthreads();

  // ---- exact re-rank: one wave per flagged (row, 64-code group) ----
  // batched strided loads (r9) + ascending-d fmaf chain (numpy-exact order)
  const int cnt = min(wcnt, WCAP);
  for (int e = w; e < cnt; e += 4) {
    const int ent = wl[e];
    const int r = ent >> 16, g = ent & 0xFFFF;
    const int code = g * 64 + lane;
    const float* cp = cbT + code;
    float dot = 0.f;
#pragma unroll
    for (int d0 = 0; d0 < DD; d0 += 64) {
      float v[64];
#pragma unroll
      for (int j = 0; j < 64; ++j) v[j] = cp[(size_t)(d0 + j) * KK];
#pragma unroll
      for (int j = 0; j < 64; ++j) dot = fmaf(zt[r][d0 + j], v[j], dot);
    }
    float bd = __fsub_rn(__fadd_rn(ArS[r], Bk[code]), __fmul_rn(2.f, dot));
    int bi = code;
#pragma unroll
    for (int off = 1; off < 64; off <<= 1) {   // lex (dist, idx) min
      float pd = __shfl_xor(bd, off);
      int pi = __shfl_xor(bi, off);
      if (pd < bd || (pd == bd && pi < bi)) { bd = pd; bi = pi; }
    }
    if (lane == 0)
      atomicMin(&rowBest[n0 + r],
                ((u64)__float_as_uint(bd) << 32) | (unsigned)bi);
  }
  __syncthreads();

  // ---- last-block-wins epilogue: second finisher of this rowTile ----
  __threadfence();                     // rowBest atomics visible device-wide
  if (t == 0) amLast = (atomicAdd(&flags[rowTile], 1) == 1);
  __syncthreads();
  if (!amLast) return;

  if (t < MT) {
    u64 key = atomicMin(&rowBest[n0 + t], 0xFFFFFFFFFFFFFFFFull);  // read
    int bi = (int)(key & 0xFFFFFFFFull);
    kwin[t] = bi;
    atomicAdd(&hist[bi], 1);
    out[(size_t)NELEM + 1 + n0 + t] = (float)bi;
  }
  __syncthreads();

  float lsum = 0.f;
  for (int it = 0; it < MT * DD / 256; ++it) {
    int li = it * 256 + t;
    int d = li >> 5, r = li & 31;
    float ze = zt[r][d];
    float zq = cb[(size_t)kwin[r] * DD + d];
    float diff = __fsub_rn(zq, ze);
    float st = __fadd_rn(ze, diff);        // z_e + (z_q - z_e)
    out[(size_t)(bimg * DD + d) * HW + hw0 + r] = st;
    lsum = fmaf(diff, diff, lsum);
  }
#pragma unroll
  for (int off = 32; off > 0; off >>= 1) lsum += __shfl_down(lsum, off);
  if (lane == 0) lred[w] = lsum;
  __syncthreads();
  if (t == 0)
    atomicAdd(loss_acc, ((lred[0] + lred[1]) + (lred[2] + lred[3])));
}

// ---------------- finalize: vq_loss + perplexity ----------------
__global__ __launch_bounds__(256) void vq_final(const int* __restrict__ hist,
                                                const float* __restrict__ loss,
                                                float* __restrict__ out) {
  __shared__ float sred[256];
  int t = threadIdx.x;
  float s = 0.f;
  for (int k = t; k < KK; k += 256) {
    float p = (float)hist[k] * (1.f / 16384.f);
    s += p * logf(p + 1e-10f);
  }
  sred[t] = s;
  __syncthreads();
  for (int off = 128; off > 0; off >>= 1) {
    if (t < off) sred[t] += sred[t + off];
    __syncthreads();
  }
  if (t == 0) {
    float L = loss[0] / (float)NELEM;
    out[NELEM] = 1.25f * L;
    out[(size_t)NELEM + 1 + NROWS] = expf(-sred[0]);
  }
}

extern "C" void kernel_launch(void* const* d_in, const int* in_sizes, int n_in,
                              void* d_out, int out_size, void* d_ws, size_t ws_size,
                              hipStream_t stream) {
  const float* z = (const float*)d_in[0];   // (16,256,32,32) fp32
  const float* cb = (const float*)d_in[1];  // (8192,256) fp32
  float* out = (float*)d_out;               // fp32: [z_q_st | loss | idx | perp]

  float* wsf = (float*)d_ws;
  int* hist = (int*)d_ws;                          // 8192 ints
  float* loss = wsf + 8192;                        // 1 (+pad)
  int* flags = (int*)d_ws + 8448;                  // 512 ints (rowTile flags)
  float* Bk = wsf + 8960;                          // 8192
  float* Arow = wsf + 17152;                       // 16384
  u64* rowBest = (u64*)(wsf + 33536);              // 16384 u64 (128 KB)
  ushort* cbB = (ushort*)(wsf + 66304);            // 2.10M ushorts (4.2 MB)
  float* cbT = wsf + 66304 + 1048576;              // 2M floats (8 MB)

  hipMemsetAsync(d_ws, 0, 8960 * sizeof(float), stream);   // hist+loss+flags
  hipMemsetAsync(rowBest, 0xFF, NROWS * sizeof(u64), stream);
  vq_prep<<<1632, 256, 0, stream>>>(z, cb, cbT, Bk, Arow, cbB);
  vq_fused<<<(NROWS / MT) * 2, 256, 0, stream>>>(z, cbT, cb, cbB, Bk, Arow,
                                                 out, hist, loss, rowBest, flags);
  vq_final<<<1, 256, 0, stream>>>(hist, loss, out);
}